// Round 1
// baseline (586.071 us; speedup 1.0000x reference)
//
#include <hip/hip_runtime.h>

typedef __bf16 bf16_t;
typedef __bf16 bf16x8 __attribute__((ext_vector_type(8)));
typedef float  f32x4  __attribute__((ext_vector_type(4)));

#define D_FEAT 512

// ---------------- convert x (f32) -> padded bf16 ----------------
__global__ void cvt_x_k(const float* __restrict__ x, bf16_t* __restrict__ xb,
                        int total, int valid) {
  int idx = (blockIdx.x * 256 + threadIdx.x) * 8;
  if (idx >= total) return;
  bf16x8 o;
  if (idx < valid) {
    const float4* p = (const float4*)(x + idx);
    float4 a = p[0], b = p[1];
    o[0] = (bf16_t)a.x; o[1] = (bf16_t)a.y; o[2] = (bf16_t)a.z; o[3] = (bf16_t)a.w;
    o[4] = (bf16_t)b.x; o[5] = (bf16_t)b.y; o[6] = (bf16_t)b.z; o[7] = (bf16_t)b.w;
  } else {
#pragma unroll
    for (int i = 0; i < 8; ++i) o[i] = (bf16_t)0.f;
  }
  *(bf16x8*)(xb + idx) = o;
}

// ------------- build combined weight WB[n][k] (bf16, [512][1024]) -------------
// WB[n][k] = k<512 ? Wl[n][k] : Wr[n][k-512]   (so C[m][n] = sum_k A[m][k]*WB[n][k])
__global__ void cvt_w_k(const float* __restrict__ Wl, const float* __restrict__ Wr,
                        bf16_t* __restrict__ WB) {
  int idx = (blockIdx.x * 256 + threadIdx.x) * 8;  // into [512][1024]
  int n = idx >> 10, k = idx & 1023;
  const float* s = (k < 512) ? (Wl + n * 512 + k) : (Wr + n * 512 + k - 512);
  const float4* p = (const float4*)s;
  float4 a = p[0], b = p[1];
  bf16x8 o;
  o[0] = (bf16_t)a.x; o[1] = (bf16_t)a.y; o[2] = (bf16_t)a.z; o[3] = (bf16_t)a.w;
  o[4] = (bf16_t)b.x; o[5] = (bf16_t)b.y; o[6] = (bf16_t)b.z; o[7] = (bf16_t)b.w;
  *(bf16x8*)(WB + idx) = o;
}

// ---------------- CSR build ----------------
__global__ void deg_k(const int* __restrict__ dst, int* __restrict__ deg, int E) {
  int e = blockIdx.x * 256 + threadIdx.x;
  if (e < E) atomicAdd(&deg[dst[e]], 1);
}

__global__ void scan_part_k(const int* __restrict__ deg, int* __restrict__ partial, int N) {
  __shared__ int sd[512];
  int tid = threadIdx.x;
  int i = blockIdx.x * 512 + tid;
  sd[tid] = (i < N) ? deg[i] : 0;
  __syncthreads();
  for (int s = 256; s > 0; s >>= 1) {
    if (tid < s) sd[tid] += sd[tid + s];
    __syncthreads();
  }
  if (tid == 0) partial[blockIdx.x] = sd[0];
}

__global__ void scan_off_k(int* __restrict__ partial, int nb, int* __restrict__ rowS, int N) {
  if (threadIdx.x == 0 && blockIdx.x == 0) {
    int run = 0;
    for (int b = 0; b < nb; ++b) { int v = partial[b]; partial[b] = run; run += v; }
    rowS[N] = run;
  }
}

__global__ void scan_blk_k(const int* __restrict__ deg, const int* __restrict__ partial,
                           int* __restrict__ rowS, int* __restrict__ cursor, int N) {
  __shared__ int sd[512];
  int tid = threadIdx.x;
  int i = blockIdx.x * 512 + tid;
  int v = (i < N) ? deg[i] : 0;
  sd[tid] = v;
  __syncthreads();
  for (int offd = 1; offd < 512; offd <<= 1) {
    int t = (tid >= offd) ? sd[tid - offd] : 0;
    __syncthreads();
    sd[tid] += t;
    __syncthreads();
  }
  int excl = sd[tid] - v + partial[blockIdx.x];
  if (i < N) { rowS[i] = excl; cursor[i] = excl; }
}

__global__ void scat_k(const int* __restrict__ src, const int* __restrict__ dst,
                       int* __restrict__ cursor, int* __restrict__ col, int E) {
  int e = blockIdx.x * 256 + threadIdx.x;
  if (e < E) {
    int d = dst[e];
    int p = atomicAdd(&cursor[d], 1);
    col[p] = src[e];
  }
}

// ---------------- mean aggregation: out[i] = mean_{j in N(i)} X[col[j]] ----------------
__global__ void agg_k(const bf16_t* __restrict__ X, const int* __restrict__ rs,
                      const int* __restrict__ col, bf16_t* __restrict__ out,
                      int N, int NPAD) {
  int lane = threadIdx.x & 63;
  int node = blockIdx.x * 4 + (threadIdx.x >> 6);
  if (node >= NPAD) return;
  bf16x8 o;
  if (node >= N) {
#pragma unroll
    for (int i = 0; i < 8; ++i) o[i] = (bf16_t)0.f;
    *(bf16x8*)(out + (size_t)node * D_FEAT + lane * 8) = o;
    return;
  }
  int s = rs[node], e = rs[node + 1];
  float acc[8] = {0.f, 0.f, 0.f, 0.f, 0.f, 0.f, 0.f, 0.f};
  for (int j = s; j < e; ++j) {
    int sn = col[j];
    bf16x8 v = *(const bf16x8*)(X + (size_t)sn * D_FEAT + lane * 8);
#pragma unroll
    for (int i = 0; i < 8; ++i) acc[i] += (float)v[i];
  }
  float sc = (e > s) ? 1.0f / (float)(e - s) : 0.f;
#pragma unroll
  for (int i = 0; i < 8; ++i) o[i] = (bf16_t)(acc[i] * sc);
  *(bf16x8*)(out + (size_t)node * D_FEAT + lane * 8) = o;
}

// ---------------- fused GEMM: out[m][n] = sum_k [A0|A1][m][k] * WB[n][k] + bias[n] ----------------
// 128x128 tile, BK=32, 4 waves (2x2), 16x16x32 bf16 MFMA, double-buffered LDS,
// global_load_lds w/ source-side XOR swizzle (LDS dest stays linear).
__device__ __forceinline__ void gload_lds16(const void* g, void* l) {
  __builtin_amdgcn_global_load_lds(
      (const __attribute__((address_space(1))) unsigned int*)g,
      (__attribute__((address_space(3))) unsigned int*)l,
      16, 0, 0);
}

template <bool RELU, typename OT>
__global__ __launch_bounds__(256) void gemm_k(
    const bf16_t* __restrict__ A0,   // K 0..511   (mean features)
    const bf16_t* __restrict__ A1,   // K 512..1023 (self features)
    const bf16_t* __restrict__ WB,   // [512][1024]
    const float* __restrict__ bias,  // [512]
    OT* __restrict__ out, int M) {
  __shared__ __align__(16) unsigned short smem[2 * 8192];  // per buf: A 4096 + B 4096 ushorts

  const int tid = threadIdx.x;
  const int lane = tid & 63;
  const int wave = tid >> 6;
  const int wr = wave >> 1, wc = wave & 1;
  const int m0 = blockIdx.y * 128;
  const int n0 = blockIdx.x * 128;

  f32x4 acc[4][4];
#pragma unroll
  for (int m = 0; m < 4; ++m)
#pragma unroll
    for (int n = 0; n < 4; ++n) acc[m][n] = (f32x4){0.f, 0.f, 0.f, 0.f};

  auto stage = [&](int buf, int kk) {
    unsigned short* sA = smem + buf * 8192;
    unsigned short* sB = sA + 4096;
    const int k0 = kk * 32;
    const bf16_t* Asrc = (k0 < 512) ? A0 : A1;
    const int k0h = k0 & 511;
#pragma unroll
    for (int s2 = 0; s2 < 2; ++s2) {
      int seg = wave * 2 + s2;
      int row = seg * 16 + (lane >> 2);
      int slot = (lane & 3) ^ (row & 3);  // source-side swizzle; read applies same XOR
      const bf16_t* ga = Asrc + (size_t)(m0 + row) * 512 + k0h + slot * 8;
      gload_lds16(ga, sA + seg * 512);
      const bf16_t* gb = WB + (size_t)(n0 + row) * 1024 + k0 + slot * 8;
      gload_lds16(gb, sB + seg * 512);
    }
  };

  stage(0, 0);
  int cur = 0;
  const int NK = 32;  // K=1024 / BK=32
  for (int kk = 0; kk < NK; ++kk) {
    __syncthreads();  // drains vmcnt -> buf[cur] staged; all waves done with buf[cur^1]
    if (kk + 1 < NK) stage(cur ^ 1, kk + 1);
    unsigned short* sA = smem + cur * 8192;
    unsigned short* sB = sA + 4096;
    bf16x8 aF[4], bF[4];
#pragma unroll
    for (int m = 0; m < 4; ++m) {
      int row = wr * 64 + m * 16 + (lane & 15);
      int slot = (lane >> 4) ^ (row & 3);
      aF[m] = *(const bf16x8*)(sA + row * 32 + slot * 8);
    }
#pragma unroll
    for (int n = 0; n < 4; ++n) {
      int row = wc * 64 + n * 16 + (lane & 15);
      int slot = (lane >> 4) ^ (row & 3);
      bF[n] = *(const bf16x8*)(sB + row * 32 + slot * 8);
    }
#pragma unroll
    for (int m = 0; m < 4; ++m)
#pragma unroll
      for (int n = 0; n < 4; ++n)
        acc[m][n] = __builtin_amdgcn_mfma_f32_16x16x32_bf16(aF[m], bF[n], acc[m][n], 0, 0, 0);
    cur ^= 1;
  }

  // epilogue: C/D layout col=lane&15, row=(lane>>4)*4+r (m89/m91-verified)
#pragma unroll
  for (int n = 0; n < 4; ++n) {
    int coln = n0 + wc * 64 + n * 16 + (lane & 15);
    float bv = bias[coln];
#pragma unroll
    for (int m = 0; m < 4; ++m) {
      int rbase = m0 + wr * 64 + m * 16 + (lane >> 4) * 4;
#pragma unroll
      for (int r = 0; r < 4; ++r) {
        int row = rbase + r;
        if (row < M) {
          float v = acc[m][n][r] + bv;
          if (RELU) v = fmaxf(v, 0.f);
          out[(size_t)row * 512 + coln] = (OT)v;
        }
      }
    }
  }
}

extern "C" void kernel_launch(void* const* d_in, const int* in_sizes, int n_in,
                              void* d_out, int out_size, void* d_ws, size_t ws_size,
                              hipStream_t stream) {
  const float* x   = (const float*)d_in[0];
  const int*   ei  = (const int*)d_in[1];
  const float* Wl1 = (const float*)d_in[2];
  const float* Wr1 = (const float*)d_in[3];
  const float* b1  = (const float*)d_in[4];
  const float* Wl2 = (const float*)d_in[5];
  const float* Wr2 = (const float*)d_in[6];
  const float* b2  = (const float*)d_in[7];

  const int N = in_sizes[0] / 512;            // 50000
  const int E = in_sizes[1] / 2;              // 800000
  const int NPAD = ((N + 127) / 128) * 128;   // 50048
  const int* srcp = ei;
  const int* dstp = ei + E;

  char* ws = (char*)d_ws;
  size_t off = 0;
  auto alloc = [&](size_t sz) -> char* {
    char* p = ws + off;
    off += sz;
    off = (off + 255) & ~(size_t)255;
    return p;
  };

  bf16_t* xb    = (bf16_t*)alloc((size_t)NPAD * 512 * 2);
  bf16_t* hb    = (bf16_t*)alloc((size_t)NPAD * 512 * 2);
  bf16_t* meanb = (bf16_t*)alloc((size_t)NPAD * 512 * 2);
  bf16_t* WB1   = (bf16_t*)alloc((size_t)512 * 1024 * 2);
  bf16_t* WB2   = (bf16_t*)alloc((size_t)512 * 1024 * 2);
  int* deg      = (int*)alloc((size_t)N * 4);
  int* rowS     = (int*)alloc((size_t)(N + 8) * 4);
  int* cursor   = (int*)alloc((size_t)N * 4);
  int* partial  = (int*)alloc(4096);
  int* colb     = (int*)alloc((size_t)E * 4);
  (void)ws_size; (void)n_in; (void)out_size;

  hipMemsetAsync(deg, 0, (size_t)N * 4, stream);

  {
    int total = NPAD * 512, valid = N * 512;
    cvt_x_k<<<dim3((total / 8 + 255) / 256), dim3(256), 0, stream>>>(x, xb, total, valid);
  }
  cvt_w_k<<<dim3(256), dim3(256), 0, stream>>>(Wl1, Wr1, WB1);
  cvt_w_k<<<dim3(256), dim3(256), 0, stream>>>(Wl2, Wr2, WB2);

  deg_k<<<dim3((E + 255) / 256), dim3(256), 0, stream>>>(dstp, deg, E);

  int NB = (N + 511) / 512;  // 98
  scan_part_k<<<dim3(NB), dim3(512), 0, stream>>>(deg, partial, N);
  scan_off_k<<<dim3(1), dim3(64), 0, stream>>>(partial, NB, rowS, N);
  scan_blk_k<<<dim3(NB), dim3(512), 0, stream>>>(deg, partial, rowS, cursor, N);
  scat_k<<<dim3((E + 255) / 256), dim3(256), 0, stream>>>(srcp, dstp, cursor, colb, E);

  // layer 1
  agg_k<<<dim3(NPAD / 4), dim3(256), 0, stream>>>(xb, rowS, colb, meanb, N, NPAD);
  dim3 grid(4, NPAD / 128);
  gemm_k<true, bf16_t><<<grid, dim3(256), 0, stream>>>(meanb, xb, WB1, b1, hb, N);

  // layer 2
  agg_k<<<dim3(NPAD / 4), dim3(256), 0, stream>>>(hb, rowS, colb, meanb, N, NPAD);
  gemm_k<false, float><<<grid, dim3(256), 0, stream>>>(meanb, hb, WB2, b2, (float*)d_out, N);
}

// Round 2
// 568.481 us; speedup vs baseline: 1.0309x; 1.0309x over previous
//
#include <hip/hip_runtime.h>

typedef __bf16 bf16_t;
typedef __bf16 bf16x8 __attribute__((ext_vector_type(8)));
typedef float  f32x4  __attribute__((ext_vector_type(4)));

#define D_FEAT 512

// ---------------- convert x (f32) -> padded bf16 ----------------
__global__ void cvt_x_k(const float* __restrict__ x, bf16_t* __restrict__ xb,
                        int total, int valid) {
  int idx = (blockIdx.x * 256 + threadIdx.x) * 8;
  if (idx >= total) return;
  bf16x8 o;
  if (idx < valid) {
    const float4* p = (const float4*)(x + idx);
    float4 a = p[0], b = p[1];
    o[0] = (bf16_t)a.x; o[1] = (bf16_t)a.y; o[2] = (bf16_t)a.z; o[3] = (bf16_t)a.w;
    o[4] = (bf16_t)b.x; o[5] = (bf16_t)b.y; o[6] = (bf16_t)b.z; o[7] = (bf16_t)b.w;
  } else {
#pragma unroll
    for (int i = 0; i < 8; ++i) o[i] = (bf16_t)0.f;
  }
  *(bf16x8*)(xb + idx) = o;
}

// ------------- build combined weight WB[n][k] (bf16, [512][1024]) -------------
__global__ void cvt_w_k(const float* __restrict__ Wl, const float* __restrict__ Wr,
                        bf16_t* __restrict__ WB) {
  int idx = (blockIdx.x * 256 + threadIdx.x) * 8;  // into [512][1024]
  int n = idx >> 10, k = idx & 1023;
  const float* s = (k < 512) ? (Wl + n * 512 + k) : (Wr + n * 512 + k - 512);
  const float4* p = (const float4*)s;
  float4 a = p[0], b = p[1];
  bf16x8 o;
  o[0] = (bf16_t)a.x; o[1] = (bf16_t)a.y; o[2] = (bf16_t)a.z; o[3] = (bf16_t)a.w;
  o[4] = (bf16_t)b.x; o[5] = (bf16_t)b.y; o[6] = (bf16_t)b.z; o[7] = (bf16_t)b.w;
  *(bf16x8*)(WB + idx) = o;
}

// ---------------- CSR build ----------------
__global__ void deg_k(const int* __restrict__ dst, int* __restrict__ deg, int E) {
  int e = blockIdx.x * 256 + threadIdx.x;
  if (e < E) atomicAdd(&deg[dst[e]], 1);
}

__global__ void scan_part_k(const int* __restrict__ deg, int* __restrict__ partial, int N) {
  __shared__ int sd[512];
  int tid = threadIdx.x;
  int i = blockIdx.x * 512 + tid;
  sd[tid] = (i < N) ? deg[i] : 0;
  __syncthreads();
  for (int s = 256; s > 0; s >>= 1) {
    if (tid < s) sd[tid] += sd[tid + s];
    __syncthreads();
  }
  if (tid == 0) partial[blockIdx.x] = sd[0];
}

__global__ void scan_off_k(int* __restrict__ partial, int nb, int* __restrict__ rowS, int N) {
  if (threadIdx.x == 0 && blockIdx.x == 0) {
    int run = 0;
    for (int b = 0; b < nb; ++b) { int v = partial[b]; partial[b] = run; run += v; }
    rowS[N] = run;
  }
}

__global__ void scan_blk_k(const int* __restrict__ deg, const int* __restrict__ partial,
                           int* __restrict__ rowS, int* __restrict__ cursor, int N) {
  __shared__ int sd[512];
  int tid = threadIdx.x;
  int i = blockIdx.x * 512 + tid;
  int v = (i < N) ? deg[i] : 0;
  sd[tid] = v;
  __syncthreads();
  for (int offd = 1; offd < 512; offd <<= 1) {
    int t = (tid >= offd) ? sd[tid - offd] : 0;
    __syncthreads();
    sd[tid] += t;
    __syncthreads();
  }
  int excl = sd[tid] - v + partial[blockIdx.x];
  if (i < N) { rowS[i] = excl; cursor[i] = excl; }
}

__global__ void scat_k(const int* __restrict__ src, const int* __restrict__ dst,
                       int* __restrict__ cursor, int* __restrict__ col, int E) {
  int e = blockIdx.x * 256 + threadIdx.x;
  if (e < E) {
    int d = dst[e];
    int p = atomicAdd(&cursor[d], 1);
    col[p] = src[e];
  }
}

// ---------------- mean aggregation: out[i] = mean_{j in N(i)} X[col[j]] ----------------
// 1 wave per node; 8-deep gather pipelining for memory-level parallelism.
__global__ __launch_bounds__(256) void agg_k(const bf16_t* __restrict__ X,
                                             const int* __restrict__ rs,
                                             const int* __restrict__ col,
                                             bf16_t* __restrict__ out,
                                             int N, int NPAD) {
  const int lane = threadIdx.x & 63;
  const int node = blockIdx.x * 4 + (threadIdx.x >> 6);
  if (node >= NPAD) return;
  const size_t obase = (size_t)node * D_FEAT + lane * 8;
  bf16x8 o;
  if (node >= N) {
#pragma unroll
    for (int i = 0; i < 8; ++i) o[i] = (bf16_t)0.f;
    *(bf16x8*)(out + obase) = o;
    return;
  }
  const int s = rs[node], e = rs[node + 1];
  const int loff = lane * 8;
  float acc[8] = {0.f, 0.f, 0.f, 0.f, 0.f, 0.f, 0.f, 0.f};
  int j = s;
  // 8-deep: 8 independent 1KB row-gathers in flight per wave
  for (; j + 8 <= e; j += 8) {
    int c0 = col[j + 0], c1 = col[j + 1], c2 = col[j + 2], c3 = col[j + 3];
    int c4 = col[j + 4], c5 = col[j + 5], c6 = col[j + 6], c7 = col[j + 7];
    bf16x8 v0 = *(const bf16x8*)(X + (size_t)c0 * D_FEAT + loff);
    bf16x8 v1 = *(const bf16x8*)(X + (size_t)c1 * D_FEAT + loff);
    bf16x8 v2 = *(const bf16x8*)(X + (size_t)c2 * D_FEAT + loff);
    bf16x8 v3 = *(const bf16x8*)(X + (size_t)c3 * D_FEAT + loff);
    bf16x8 v4 = *(const bf16x8*)(X + (size_t)c4 * D_FEAT + loff);
    bf16x8 v5 = *(const bf16x8*)(X + (size_t)c5 * D_FEAT + loff);
    bf16x8 v6 = *(const bf16x8*)(X + (size_t)c6 * D_FEAT + loff);
    bf16x8 v7 = *(const bf16x8*)(X + (size_t)c7 * D_FEAT + loff);
#pragma unroll
    for (int i = 0; i < 8; ++i) {
      float s01 = (float)v0[i] + (float)v1[i];
      float s23 = (float)v2[i] + (float)v3[i];
      float s45 = (float)v4[i] + (float)v5[i];
      float s67 = (float)v6[i] + (float)v7[i];
      acc[i] += (s01 + s23) + (s45 + s67);
    }
  }
  for (; j + 2 <= e; j += 2) {
    int c0 = col[j + 0], c1 = col[j + 1];
    bf16x8 v0 = *(const bf16x8*)(X + (size_t)c0 * D_FEAT + loff);
    bf16x8 v1 = *(const bf16x8*)(X + (size_t)c1 * D_FEAT + loff);
#pragma unroll
    for (int i = 0; i < 8; ++i) acc[i] += (float)v0[i] + (float)v1[i];
  }
  for (; j < e; ++j) {
    int c0 = col[j];
    bf16x8 v0 = *(const bf16x8*)(X + (size_t)c0 * D_FEAT + loff);
#pragma unroll
    for (int i = 0; i < 8; ++i) acc[i] += (float)v0[i];
  }
  float sc = (e > s) ? 1.0f / (float)(e - s) : 0.f;
#pragma unroll
  for (int i = 0; i < 8; ++i) o[i] = (bf16_t)(acc[i] * sc);
  *(bf16x8*)(out + obase) = o;
}

// ---------------- fused GEMM: out[m][n] = sum_k [A0|A1][m][k] * WB[n][k] + bias[n] ----------------
__device__ __forceinline__ void gload_lds16(const void* g, void* l) {
  __builtin_amdgcn_global_load_lds(
      (const __attribute__((address_space(1))) unsigned int*)g,
      (__attribute__((address_space(3))) unsigned int*)l,
      16, 0, 0);
}

template <bool RELU, typename OT>
__global__ __launch_bounds__(256) void gemm_k(
    const bf16_t* __restrict__ A0,   // K 0..511   (mean features)
    const bf16_t* __restrict__ A1,   // K 512..1023 (self features)
    const bf16_t* __restrict__ WB,   // [512][1024]
    const float* __restrict__ bias,  // [512]
    OT* __restrict__ out, int M) {
  __shared__ __align__(16) unsigned short smem[2 * 8192];  // per buf: A 4096 + B 4096 ushorts

  const int tid = threadIdx.x;
  const int lane = tid & 63;
  const int wave = tid >> 6;
  const int wr = wave >> 1, wc = wave & 1;
  const int m0 = blockIdx.y * 128;
  const int n0 = blockIdx.x * 128;

  f32x4 acc[4][4];
#pragma unroll
  for (int m = 0; m < 4; ++m)
#pragma unroll
    for (int n = 0; n < 4; ++n) acc[m][n] = (f32x4){0.f, 0.f, 0.f, 0.f};

  auto stage = [&](int buf, int kk) {
    unsigned short* sA = smem + buf * 8192;
    unsigned short* sB = sA + 4096;
    const int k0 = kk * 32;
    const bf16_t* Asrc = (k0 < 512) ? A0 : A1;
    const int k0h = k0 & 511;
#pragma unroll
    for (int s2 = 0; s2 < 2; ++s2) {
      int seg = wave * 2 + s2;
      int row = seg * 16 + (lane >> 2);
      int slot = (lane & 3) ^ (row & 3);  // source-side swizzle; read applies same XOR
      const bf16_t* ga = Asrc + (size_t)(m0 + row) * 512 + k0h + slot * 8;
      gload_lds16(ga, sA + seg * 512);
      const bf16_t* gb = WB + (size_t)(n0 + row) * 1024 + k0 + slot * 8;
      gload_lds16(gb, sB + seg * 512);
    }
  };

  stage(0, 0);
  int cur = 0;
  const int NK = 32;  // K=1024 / BK=32
  for (int kk = 0; kk < NK; ++kk) {
    __syncthreads();
    if (kk + 1 < NK) stage(cur ^ 1, kk + 1);
    unsigned short* sA = smem + cur * 8192;
    unsigned short* sB = sA + 4096;
    bf16x8 aF[4], bF[4];
#pragma unroll
    for (int m = 0; m < 4; ++m) {
      int row = wr * 64 + m * 16 + (lane & 15);
      int slot = (lane >> 4) ^ (row & 3);
      aF[m] = *(const bf16x8*)(sA + row * 32 + slot * 8);
    }
#pragma unroll
    for (int n = 0; n < 4; ++n) {
      int row = wc * 64 + n * 16 + (lane & 15);
      int slot = (lane >> 4) ^ (row & 3);
      bF[n] = *(const bf16x8*)(sB + row * 32 + slot * 8);
    }
#pragma unroll
    for (int m = 0; m < 4; ++m)
#pragma unroll
      for (int n = 0; n < 4; ++n)
        acc[m][n] = __builtin_amdgcn_mfma_f32_16x16x32_bf16(aF[m], bF[n], acc[m][n], 0, 0, 0);
    cur ^= 1;
  }

  // epilogue: C/D layout col=lane&15, row=(lane>>4)*4+r
#pragma unroll
  for (int n = 0; n < 4; ++n) {
    int coln = n0 + wc * 64 + n * 16 + (lane & 15);
    float bv = bias[coln];
#pragma unroll
    for (int m = 0; m < 4; ++m) {
      int rbase = m0 + wr * 64 + m * 16 + (lane >> 4) * 4;
#pragma unroll
      for (int r = 0; r < 4; ++r) {
        int row = rbase + r;
        if (row < M) {
          float v = acc[m][n][r] + bv;
          if (RELU) v = fmaxf(v, 0.f);
          out[(size_t)row * 512 + coln] = (OT)v;
        }
      }
    }
  }
}

extern "C" void kernel_launch(void* const* d_in, const int* in_sizes, int n_in,
                              void* d_out, int out_size, void* d_ws, size_t ws_size,
                              hipStream_t stream) {
  const float* x   = (const float*)d_in[0];
  const int*   ei  = (const int*)d_in[1];
  const float* Wl1 = (const float*)d_in[2];
  const float* Wr1 = (const float*)d_in[3];
  const float* b1  = (const float*)d_in[4];
  const float* Wl2 = (const float*)d_in[5];
  const float* Wr2 = (const float*)d_in[6];
  const float* b2  = (const float*)d_in[7];

  const int N = in_sizes[0] / 512;            // 50000
  const int E = in_sizes[1] / 2;              // 800000
  const int NPAD = ((N + 127) / 128) * 128;   // 50048
  const int* srcp = ei;
  const int* dstp = ei + E;

  char* ws = (char*)d_ws;
  size_t off = 0;
  auto alloc = [&](size_t sz) -> char* {
    char* p = ws + off;
    off += sz;
    off = (off + 255) & ~(size_t)255;
    return p;
  };

  bf16_t* xb    = (bf16_t*)alloc((size_t)NPAD * 512 * 2);
  bf16_t* hb    = (bf16_t*)alloc((size_t)NPAD * 512 * 2);
  bf16_t* meanb = (bf16_t*)alloc((size_t)NPAD * 512 * 2);
  bf16_t* WB1   = (bf16_t*)alloc((size_t)512 * 1024 * 2);
  bf16_t* WB2   = (bf16_t*)alloc((size_t)512 * 1024 * 2);
  int* deg      = (int*)alloc((size_t)N * 4);
  int* rowS     = (int*)alloc((size_t)(N + 8) * 4);
  int* cursor   = (int*)alloc((size_t)N * 4);
  int* partial  = (int*)alloc(4096);
  int* colb     = (int*)alloc((size_t)E * 4);
  (void)ws_size; (void)n_in; (void)out_size;

  hipMemsetAsync(deg, 0, (size_t)N * 4, stream);

  {
    int total = NPAD * 512, valid = N * 512;
    cvt_x_k<<<dim3((total / 8 + 255) / 256), dim3(256), 0, stream>>>(x, xb, total, valid);
  }
  cvt_w_k<<<dim3(256), dim3(256), 0, stream>>>(Wl1, Wr1, WB1);
  cvt_w_k<<<dim3(256), dim3(256), 0, stream>>>(Wl2, Wr2, WB2);

  deg_k<<<dim3((E + 255) / 256), dim3(256), 0, stream>>>(dstp, deg, E);

  int NB = (N + 511) / 512;  // 98
  scan_part_k<<<dim3(NB), dim3(512), 0, stream>>>(deg, partial, N);
  scan_off_k<<<dim3(1), dim3(64), 0, stream>>>(partial, NB, rowS, N);
  scan_blk_k<<<dim3(NB), dim3(512), 0, stream>>>(deg, partial, rowS, cursor, N);
  scat_k<<<dim3((E + 255) / 256), dim3(256), 0, stream>>>(srcp, dstp, cursor, colb, E);

  // layer 1
  agg_k<<<dim3(NPAD / 4), dim3(256), 0, stream>>>(xb, rowS, colb, meanb, N, NPAD);
  dim3 grid(4, NPAD / 128);
  gemm_k<true, bf16_t><<<grid, dim3(256), 0, stream>>>(meanb, xb, WB1, b1, hb, N);

  // layer 2
  agg_k<<<dim3(NPAD / 4), dim3(256), 0, stream>>>(hb, rowS, colb, meanb, N, NPAD);
  gemm_k<false, float><<<grid, dim3(256), 0, stream>>>(meanb, hb, WB2, b2, (float*)d_out, N);
}